// Round 14
// baseline (205.303 us; speedup 1.0000x reference)
//
#include <hip/hip_runtime.h>

typedef unsigned int uint;
typedef unsigned short ushort;
typedef __attribute__((ext_vector_type(8))) short short8v;
typedef __attribute__((ext_vector_type(4))) float f32x4;

#define NBMAX 512      // max coarse buckets (bucket = 256 nodes, N <= 131072)
#define BSHIFT 8       // 256 nodes per bucket

__device__ __forceinline__ ushort f2bf(float f) {
    uint u = __float_as_uint(f);
    u += 0x7fffu + ((u >> 16) & 1u);   // round-to-nearest-even
    return (ushort)(u >> 16);
}

// ---------------- binned CSR build ----------------
// Pass A hist (+ W1/W2 transpose/convert/swizzle piggybacked; bcnt pre-zeroed by memset).

__global__ void hist_prep(const int* __restrict__ dst, int* __restrict__ bcnt,
                          int E, int nbk,
                          const float* __restrict__ W1, const float* __restrict__ W2,
                          ushort* __restrict__ Wt1s, ushort* __restrict__ Wt2s) {
    __shared__ int s[NBMAX];
    int t = threadIdx.x;
    for (int i = t; i < nbk; i += 256) s[i] = 0;
    __syncthreads();
    int i0 = blockIdx.x * 4096 + t;
#pragma unroll
    for (int k = 0; k < 16; ++k) {
        int i = i0 + k * 256;
        if (i < E) atomicAdd(&s[dst[i] >> BSHIFT], 1);
    }
    __syncthreads();
    for (int i = t; i < nbk; i += 256) if (s[i] > 0) atomicAdd(&bcnt[i], s[i]);

    // W images: [n][k] bf16, byte ^ ((n&7)<<4)
    int g = blockIdx.x * 256 + t;
    int total = gridDim.x * 256;
    for (int idx = g; idx < 128 * 128; idx += total) {
        int nn = idx >> 7, kk = idx & 127;
        uint byte = (uint)nn * 256u + (uint)kk * 2u;
        byte ^= (uint)((nn & 7) << 4);
        Wt1s[byte >> 1] = f2bf(W1[kk * 128 + nn]);
    }
    for (int idx = g; idx < 64 * 128; idx += total) {
        int nn = idx >> 7, kk = idx & 127;
        uint byte = (uint)nn * 256u + (uint)kk * 2u;
        byte ^= (uint)((nn & 7) << 4);
        Wt2s[byte >> 1] = f2bf(W2[kk * 64 + nn]);
    }
}

// single block, 512 threads: exclusive scan bcnt -> bstart (kept) and bcur (mutated later)
__global__ void bucket_scan(const int* __restrict__ bcnt, int* __restrict__ bstart,
                            int* __restrict__ bcur, int nbk) {
    __shared__ int s[512];
    int t = threadIdx.x;
    int v = (t < nbk) ? bcnt[t] : 0;
    s[t] = v;
    __syncthreads();
    for (int o = 1; o < 512; o <<= 1) {
        int tv = (t >= o) ? s[t - o] : 0;
        __syncthreads();
        s[t] += tv;
        __syncthreads();
    }
    if (t < nbk) {
        int ex = s[t] - v;
        bstart[t] = ex;
        bcur[t] = ex;
    }
}

__global__ void bucket_scatter(const int* __restrict__ src, const int* __restrict__ dst,
                               int* __restrict__ bcur, int* __restrict__ tsw, int E) {
    __shared__ int cnt[NBMAX];
    __shared__ int base[NBMAX];
    int t = threadIdx.x;
    for (int i = t; i < NBMAX; i += 256) cnt[i] = 0;
    __syncthreads();
    int i0 = blockIdx.x * 4096 + t;
    int p_[16], b_[16], r_[16];
#pragma unroll
    for (int k = 0; k < 16; ++k) {
        int i = i0 + k * 256;
        if (i < E) {
            int s = src[i], d = dst[i];
            int bb = d >> BSHIFT;
            b_[k] = bb;
            p_[k] = s | ((d & ((1 << BSHIFT) - 1)) << 17);
            r_[k] = atomicAdd(&cnt[bb], 1);
        } else {
            b_[k] = -1;
        }
    }
    __syncthreads();
    for (int i = t; i < NBMAX; i += 256) if (cnt[i] > 0) base[i] = atomicAdd(&bcur[i], cnt[i]);
    __syncthreads();
#pragma unroll
    for (int k = 0; k < 16; ++k) {
        if (b_[k] >= 0) {
            int p = base[b_[k]] + r_[k];
            tsw[p] = p_[k];
        }
    }
}

// Pass B: one block per bucket. LDS counting-sort by local dst; the LDS histogram IS
// the in-degree -> emits dinv, rp, self-loops, and the bucket's contiguous edata region.
__global__ void sort_bucket(const int* __restrict__ tsw, const int* __restrict__ bstart,
                            float* __restrict__ dinv, int* __restrict__ rp,
                            int* __restrict__ edata, int N, int E, int nbk) {
    __shared__ int cnt[256];
    __shared__ int cursor[256];
    int b = blockIdx.x;
    int t = threadIdx.x;
    int estart = bstart[b];
    int eend = (b + 1 < nbk) ? bstart[b + 1] : E;

    cnt[t] = 0;
    __syncthreads();
    for (int i = estart + t; i < eend; i += 256) {
        atomicAdd(&cnt[(uint)tsw[i] >> 17], 1);
    }
    __syncthreads();

    int node = (b << BSHIFT) + t;
    int self = (node < N) ? 1 : 0;
    int deg = cnt[t];
    int v = deg + self;
    cursor[t] = v;
    __syncthreads();
    for (int o = 1; o < 256; o <<= 1) {
        int tv = (t >= o) ? cursor[t - o] : 0;
        __syncthreads();
        cursor[t] += tv;
        __syncthreads();
    }
    int ex = cursor[t] - v;                       // exclusive local offset
    int gbase = estart + (b << BSHIFT);           // edges + self loops before this bucket

    if (node < N) {
        dinv[node] = rsqrtf((float)(deg + 1));    // + self loop
        rp[node] = gbase + ex;
        edata[gbase + ex] = node;                 // self loop at slot 0 (src == dst)
    }
    if (b == nbk - 1 && t == 0) rp[N] = E + N;
    cursor[t] = ex + self;
    __syncthreads();

    for (int i = estart + t; i < eend; i += 256) {
        uint rec = (uint)tsw[i];
        int pos = gbase + atomicAdd(&cursor[rec >> 17], 1);
        edata[pos] = (int)(rec & 0x1FFFFu);
    }
}

// ---------------- MFMA GEMM layer 1: H1[row][0..128) = dinv[row] * (X[row] @ W1) ----------------
// Zeroes the pad row at index n (blockIdx 0).
// mfma_f32_16x16x32_bf16: A row=lane&15, k=(lane>>4)*8+i ; B col=lane&15, same k ;
// D col=lane&15, row=(lane>>4)*4+reg

__launch_bounds__(256)
__global__ void gemm_mfma128(const float* __restrict__ X, const ushort* __restrict__ Wimg,
                             ushort* __restrict__ H, const float* __restrict__ dinv, int n) {
    constexpr int NT = 8;
    if (blockIdx.x == 0 && threadIdx.x < 128) H[(size_t)n * 128 + threadIdx.x] = 0;
    __shared__ ushort sW[128 * 128];
    {
        const uint4* src = (const uint4*)Wimg;
        uint4* dst = (uint4*)sW;
        for (int i = threadIdx.x; i < 128 * 128 * 2 / 16; i += 256) dst[i] = src[i];
    }
    __syncthreads();

    const int w  = threadIdx.x >> 6;
    const int l  = threadIdx.x & 63;
    const int lm = l & 15, lk = l >> 4;
    const int row_base = blockIdx.x * 128 + w * 32;

    f32x4 acc[2][NT];
#pragma unroll
    for (int mt = 0; mt < 2; ++mt)
#pragma unroll
        for (int nt = 0; nt < NT; ++nt) {
            f32x4 z = {0.f, 0.f, 0.f, 0.f};
            acc[mt][nt] = z;
        }

    int r0 = row_base + lm;
    int r1 = row_base + 16 + lm;
    int r0c = r0 < n ? r0 : n - 1;
    int r1c = r1 < n ? r1 : n - 1;

#pragma unroll
    for (int kb = 0; kb < 4; ++kb) {
        short8v a0, a1;
        const float* p0 = X + (size_t)r0c * 128 + kb * 32 + lk * 8;
        const float* p1 = X + (size_t)r1c * 128 + kb * 32 + lk * 8;
        float4 u0 = *(const float4*)p0;
        float4 v0 = *(const float4*)(p0 + 4);
        float4 u1 = *(const float4*)p1;
        float4 v1 = *(const float4*)(p1 + 4);
        a0[0] = (short)f2bf(u0.x); a0[1] = (short)f2bf(u0.y);
        a0[2] = (short)f2bf(u0.z); a0[3] = (short)f2bf(u0.w);
        a0[4] = (short)f2bf(v0.x); a0[5] = (short)f2bf(v0.y);
        a0[6] = (short)f2bf(v0.z); a0[7] = (short)f2bf(v0.w);
        a1[0] = (short)f2bf(u1.x); a1[1] = (short)f2bf(u1.y);
        a1[2] = (short)f2bf(u1.z); a1[3] = (short)f2bf(u1.w);
        a1[4] = (short)f2bf(v1.x); a1[5] = (short)f2bf(v1.y);
        a1[6] = (short)f2bf(v1.z); a1[7] = (short)f2bf(v1.w);
#pragma unroll
        for (int nt = 0; nt < NT; ++nt) {
            int nn = nt * 16 + lm;
            uint byte = (uint)nn * 256u + (uint)kb * 64u + (uint)lk * 16u;
            byte ^= (uint)((nn & 7) << 4);
            short8v b = *(const short8v*)((const char*)sW + byte);
            acc[0][nt] = __builtin_amdgcn_mfma_f32_16x16x32_bf16(a0, b, acc[0][nt], 0, 0, 0);
            acc[1][nt] = __builtin_amdgcn_mfma_f32_16x16x32_bf16(a1, b, acc[1][nt], 0, 0, 0);
        }
    }

    float dvs[2][4];
#pragma unroll
    for (int mt = 0; mt < 2; ++mt)
#pragma unroll
        for (int r = 0; r < 4; ++r) {
            int row = row_base + mt * 16 + lk * 4 + r;
            dvs[mt][r] = (row < n) ? dinv[row] : 0.f;
        }
#pragma unroll
    for (int mt = 0; mt < 2; ++mt)
#pragma unroll
        for (int nt = 0; nt < NT; ++nt)
#pragma unroll
            for (int r = 0; r < 4; ++r) {
                int row = row_base + mt * 16 + lk * 4 + r;
                if (row < n) H[(size_t)row * 128 + nt * 16 + lm] = f2bf(acc[mt][nt][r] * dvs[mt][r]);
            }
}

// ---------------- fused layer-1 agg + layer-2 GEMM ----------------
// Gather phase: 16-lane quarter per node, uint4/lane, 16 loads in flight;
// computes A1row = relu(dinv[node]*sum H1[src] + b1) in registers.
// Pack to bf16 -> swizzled LDS tile sA[16][128]; barrier; each wave MFMAs the 16-node
// tile against W2 (LDS image) for its 16-col n-tile; writes H2 = dinv*(A1@W2).

__launch_bounds__(256)
__global__ void agg128_w2(const ushort* __restrict__ H, const int* __restrict__ rp,
                          const int* __restrict__ edata, const float* __restrict__ dinv,
                          const float* __restrict__ b1, const ushort* __restrict__ W2img,
                          ushort* __restrict__ H2, int N) {
    __shared__ ushort sW[64 * 128];   // 16KB W2 image (swizzled)
    __shared__ ushort sA[16 * 128];   // 4KB A1 tile (swizzled)
    {
        const uint4* s = (const uint4*)W2img;
        uint4* d = (uint4*)sW;
        for (int i = threadIdx.x; i < 64 * 128 * 2 / 16; i += 256) d[i] = s[i];
    }
    if (blockIdx.x == 0 && threadIdx.x < 64) H2[(size_t)N * 64 + threadIdx.x] = 0;

    const int lane = threadIdx.x & 63;
    const int c = lane & 15;                      // lane in quarter
    const int qb = lane & 48;                     // quarter base within wave
    const int nl = threadIdx.x >> 4;              // local node 0..15
    const int node = blockIdx.x * 16 + nl;

    float a0 = 0.f, a1 = 0.f, a2 = 0.f, a3 = 0.f;
    float a4 = 0.f, a5 = 0.f, a6 = 0.f, a7 = 0.f;

    if (node < N) {
        int e = rp[node], end = rp[node + 1];
        for (; e < end; e += 16) {
            int idx = e + c;
            int md = (idx < end) ? edata[idx] : N;    // zero row for padding slots
#pragma unroll
            for (int j = 0; j < 16; ++j) {
                int si = __shfl(md, qb + j);
                uint4 hv = *(const uint4*)&H[(size_t)si * 128 + c * 8];
                a0 += __uint_as_float(hv.x << 16);
                a1 += __uint_as_float(hv.x & 0xffff0000u);
                a2 += __uint_as_float(hv.y << 16);
                a3 += __uint_as_float(hv.y & 0xffff0000u);
                a4 += __uint_as_float(hv.z << 16);
                a5 += __uint_as_float(hv.z & 0xffff0000u);
                a6 += __uint_as_float(hv.w << 16);
                a7 += __uint_as_float(hv.w & 0xffff0000u);
            }
        }
        float dg = dinv[node];
        float4 bv0 = *(const float4*)&b1[c * 8];
        float4 bv1 = *(const float4*)&b1[c * 8 + 4];
        a0 = fmaxf(dg * a0 + bv0.x, 0.f); a1 = fmaxf(dg * a1 + bv0.y, 0.f);
        a2 = fmaxf(dg * a2 + bv0.z, 0.f); a3 = fmaxf(dg * a3 + bv0.w, 0.f);
        a4 = fmaxf(dg * a4 + bv1.x, 0.f); a5 = fmaxf(dg * a5 + bv1.y, 0.f);
        a6 = fmaxf(dg * a6 + bv1.z, 0.f); a7 = fmaxf(dg * a7 + bv1.w, 0.f);
    } else {
        a0 = a1 = a2 = a3 = a4 = a5 = a6 = a7 = 0.f;   // zero A rows for pad nodes
    }
    uint4 pk;
    pk.x = (uint)f2bf(a0) | ((uint)f2bf(a1) << 16);
    pk.y = (uint)f2bf(a2) | ((uint)f2bf(a3) << 16);
    pk.z = (uint)f2bf(a4) | ((uint)f2bf(a5) << 16);
    pk.w = (uint)f2bf(a6) | ((uint)f2bf(a7) << 16);
    uint wbyte = (uint)nl * 256u + (((uint)c * 16u) ^ ((uint)(nl & 7) << 4));
    *(uint4*)((char*)sA + wbyte) = pk;
    __syncthreads();

    // MFMA: 16 nodes x 128k @ 128k x 64 -> wave w computes cols [w*16, w*16+16)
    const int w  = threadIdx.x >> 6;
    const int lm = lane & 15, lk = lane >> 4;
    const int nn = w * 16 + lm;
    f32x4 acc = {0.f, 0.f, 0.f, 0.f};
#pragma unroll
    for (int kb = 0; kb < 4; ++kb) {
        uint ka = (uint)(kb * 64 + lk * 16);
        short8v af = *(const short8v*)((const char*)sA + (uint)lm * 256u + (ka ^ ((uint)(lm & 7) << 4)));
        short8v bf = *(const short8v*)((const char*)sW + (uint)nn * 256u + (ka ^ ((uint)(nn & 7) << 4)));
        acc = __builtin_amdgcn_mfma_f32_16x16x32_bf16(af, bf, acc, 0, 0, 0);
    }
#pragma unroll
    for (int r = 0; r < 4; ++r) {
        int n2 = blockIdx.x * 16 + lk * 4 + r;
        if (n2 < N) H2[(size_t)n2 * 64 + w * 16 + lm] = f2bf(acc[r] * dinv[n2]);
    }
}

// ---------------- layer-2 aggregation: 8-lane EIGHTH per node, uint4/lane ----------------
// H2 is [N+1][64] bf16 (pre-scaled by dinv[src]) with zero pad row at N.
// out[node] = dinv[node] * sum_e H2[src_e] + b2; fp32 out.
// Lane c owns dims [8c,8c+8); 16-slot batches via dual metadata words; 16 uint4
// loads in flight per wave (2x outstanding bytes vs uint2 form).

__launch_bounds__(256)
__global__ void agg64(const ushort* __restrict__ H, const int* __restrict__ rp,
                      const int* __restrict__ edata, const float* __restrict__ dinv,
                      const float* __restrict__ bias, float* __restrict__ out, int N) {
    const int lane = threadIdx.x & 63;
    const int eb = lane & 56;                     // eighth base within wave (8-aligned)
    const int c = lane & 7;                       // lane in eighth
    const int node = blockIdx.x * 32 + (threadIdx.x >> 3);
    if (node >= N) return;                        // whole eighth exits together
    int e = rp[node], end = rp[node + 1];
    float a0 = 0.f, a1 = 0.f, a2 = 0.f, a3 = 0.f;
    float a4 = 0.f, a5 = 0.f, a6 = 0.f, a7 = 0.f;

    for (; e < end; e += 16) {
        int i0 = e + c, i1 = e + 8 + c;
        int md0 = (i0 < end) ? edata[i0] : N;     // slots 0-7
        int md1 = (i1 < end) ? edata[i1] : N;     // slots 8-15
#pragma unroll
        for (int j = 0; j < 16; ++j) {
            int si = (j < 8) ? __shfl(md0, eb + j) : __shfl(md1, eb + (j - 8));
            uint4 hv = *(const uint4*)&H[(size_t)si * 64 + c * 8];
            a0 += __uint_as_float(hv.x << 16);
            a1 += __uint_as_float(hv.x & 0xffff0000u);
            a2 += __uint_as_float(hv.y << 16);
            a3 += __uint_as_float(hv.y & 0xffff0000u);
            a4 += __uint_as_float(hv.z << 16);
            a5 += __uint_as_float(hv.z & 0xffff0000u);
            a6 += __uint_as_float(hv.w << 16);
            a7 += __uint_as_float(hv.w & 0xffff0000u);
        }
    }
    float dg = dinv[node];
    float4 bv0 = *(const float4*)&bias[c * 8];
    float4 bv1 = *(const float4*)&bias[c * 8 + 4];
    a0 = dg * a0 + bv0.x; a1 = dg * a1 + bv0.y;
    a2 = dg * a2 + bv0.z; a3 = dg * a3 + bv0.w;
    a4 = dg * a4 + bv1.x; a5 = dg * a5 + bv1.y;
    a6 = dg * a6 + bv1.z; a7 = dg * a7 + bv1.w;
    float* o = out + (size_t)node * 64 + c * 8;
    *(float4*)o       = make_float4(a0, a1, a2, a3);
    *(float4*)(o + 4) = make_float4(a4, a5, a6, a7);
}

__global__ void zero_out(float* __restrict__ out, int n) {
    int i = blockIdx.x * 256 + threadIdx.x;
    if (i < n) out[i] = 0.f;
}

// ---------------- launch ----------------

extern "C" void kernel_launch(void* const* d_in, const int* in_sizes, int n_in,
                              void* d_out, int out_size, void* d_ws, size_t ws_size,
                              hipStream_t stream) {
    const float* x  = (const float*)d_in[0];
    const int*   ei = (const int*)d_in[1];
    const float* W1 = (const float*)d_in[2];
    const float* b1 = (const float*)d_in[3];
    const float* W2 = (const float*)d_in[4];
    const float* b2 = (const float*)d_in[5];
    float* out = (float*)d_out;

    const int N = in_sizes[0] / 128;
    const int E = in_sizes[1] / 2;
    const int* srcp = ei;
    const int* dstp = ei + E;

    char* base = (char*)d_ws;
    size_t off = 0;
    auto alloc = [&](size_t bytes) -> void* {
        void* p = base + off;
        off += (bytes + 15) & ~(size_t)15;
        return p;
    };
    ushort* H1    = (ushort*)alloc((size_t)(N + 1) * 128 * 2);  // [N+1][128] + pad row
    ushort* H2    = (ushort*)alloc((size_t)(N + 1) * 64 * 2);   // [N+1][64] + pad row; aliases tsw
    ushort* Wt1s  = (ushort*)alloc(128 * 128 * 2);
    ushort* Wt2s  = (ushort*)alloc(64 * 128 * 2);
    float*  dinv  = (float*)alloc((size_t)N * 4);
    int*    rp    = (int*)alloc((size_t)(N + 1) * 4);
    int*    bcnt  = (int*)alloc(NBMAX * 4);
    int*    bstart= (int*)alloc(NBMAX * 4);
    int*    bcur  = (int*)alloc(NBMAX * 4);
    int*    edata = (int*)alloc((size_t)(E + N) * 4);

    int* tsw = (int*)H2;   // E records of 4B, dead before agg128_w2 writes H2

    int nbk = (N + (1 << BSHIFT) - 1) >> BSHIFT;
    if (off > ws_size || (size_t)E * 4 > (size_t)(N + 1) * 128 ||
        N > (1 << 17) || nbk > NBMAX) {
        zero_out<<<(out_size + 255) / 256, 256, 0, stream>>>(out, out_size);
        return;
    }
    int nchunk = (E + 4095) / 4096;

    hipMemsetAsync(bcnt, 0, NBMAX * sizeof(int), stream);
    hist_prep<<<nchunk, 256, 0, stream>>>(dstp, bcnt, E, nbk, W1, W2, Wt1s, Wt2s);
    bucket_scan<<<1, 512, 0, stream>>>(bcnt, bstart, bcur, nbk);
    bucket_scatter<<<nchunk, 256, 0, stream>>>(srcp, dstp, bcur, tsw, E);
    sort_bucket<<<nbk, 256, 0, stream>>>(tsw, bstart, dinv, rp, edata, N, E, nbk);

    gemm_mfma128<<<(N + 127) / 128, 256, 0, stream>>>(x, Wt1s, H1, dinv, N);
    agg128_w2<<<(N + 15) / 16, 256, 0, stream>>>(H1, rp, edata, dinv, b1, Wt2s, H2, N);
    agg64<<<(N + 31) / 32, 256, 0, stream>>>(H2, rp, edata, dinv, b2, out, N);
}

// Round 15
// 191.522 us; speedup vs baseline: 1.0720x; 1.0720x over previous
//
#include <hip/hip_runtime.h>

typedef unsigned int uint;
typedef unsigned short ushort;
typedef __attribute__((ext_vector_type(8))) short short8v;
typedef __attribute__((ext_vector_type(4))) float f32x4;

#define NBMAX 512      // max coarse buckets (bucket = 256 nodes, N <= 131072)
#define BSHIFT 8       // 256 nodes per bucket

__device__ __forceinline__ ushort f2bf(float f) {
    uint u = __float_as_uint(f);
    u += 0x7fffu + ((u >> 16) & 1u);   // round-to-nearest-even
    return (ushort)(u >> 16);
}

// ---------------- binned CSR build ----------------
// Pass A hist (+ W1/W2 transpose/convert/swizzle piggybacked; bcnt pre-zeroed by memset).

__global__ void hist_prep(const int* __restrict__ dst, int* __restrict__ bcnt,
                          int E, int nbk,
                          const float* __restrict__ W1, const float* __restrict__ W2,
                          ushort* __restrict__ Wt1s, ushort* __restrict__ Wt2s) {
    __shared__ int s[NBMAX];
    int t = threadIdx.x;
    for (int i = t; i < nbk; i += 256) s[i] = 0;
    __syncthreads();
    int i0 = blockIdx.x * 4096 + t;
#pragma unroll
    for (int k = 0; k < 16; ++k) {
        int i = i0 + k * 256;
        if (i < E) atomicAdd(&s[dst[i] >> BSHIFT], 1);
    }
    __syncthreads();
    for (int i = t; i < nbk; i += 256) if (s[i] > 0) atomicAdd(&bcnt[i], s[i]);

    // W images: [n][k] bf16, byte ^ ((n&7)<<4)
    int g = blockIdx.x * 256 + t;
    int total = gridDim.x * 256;
    for (int idx = g; idx < 128 * 128; idx += total) {
        int nn = idx >> 7, kk = idx & 127;
        uint byte = (uint)nn * 256u + (uint)kk * 2u;
        byte ^= (uint)((nn & 7) << 4);
        Wt1s[byte >> 1] = f2bf(W1[kk * 128 + nn]);
    }
    for (int idx = g; idx < 64 * 128; idx += total) {
        int nn = idx >> 7, kk = idx & 127;
        uint byte = (uint)nn * 256u + (uint)kk * 2u;
        byte ^= (uint)((nn & 7) << 4);
        Wt2s[byte >> 1] = f2bf(W2[kk * 64 + nn]);
    }
}

// single block, 512 threads: exclusive scan bcnt -> bstart (kept) and bcur (mutated later)
__global__ void bucket_scan(const int* __restrict__ bcnt, int* __restrict__ bstart,
                            int* __restrict__ bcur, int nbk) {
    __shared__ int s[512];
    int t = threadIdx.x;
    int v = (t < nbk) ? bcnt[t] : 0;
    s[t] = v;
    __syncthreads();
    for (int o = 1; o < 512; o <<= 1) {
        int tv = (t >= o) ? s[t - o] : 0;
        __syncthreads();
        s[t] += tv;
        __syncthreads();
    }
    if (t < nbk) {
        int ex = s[t] - v;
        bstart[t] = ex;
        bcur[t] = ex;
    }
}

__global__ void bucket_scatter(const int* __restrict__ src, const int* __restrict__ dst,
                               int* __restrict__ bcur, int* __restrict__ tsw, int E) {
    __shared__ int cnt[NBMAX];
    __shared__ int base[NBMAX];
    int t = threadIdx.x;
    for (int i = t; i < NBMAX; i += 256) cnt[i] = 0;
    __syncthreads();
    int i0 = blockIdx.x * 4096 + t;
    int p_[16], b_[16], r_[16];
#pragma unroll
    for (int k = 0; k < 16; ++k) {
        int i = i0 + k * 256;
        if (i < E) {
            int s = src[i], d = dst[i];
            int bb = d >> BSHIFT;
            b_[k] = bb;
            p_[k] = s | ((d & ((1 << BSHIFT) - 1)) << 17);
            r_[k] = atomicAdd(&cnt[bb], 1);
        } else {
            b_[k] = -1;
        }
    }
    __syncthreads();
    for (int i = t; i < NBMAX; i += 256) if (cnt[i] > 0) base[i] = atomicAdd(&bcur[i], cnt[i]);
    __syncthreads();
#pragma unroll
    for (int k = 0; k < 16; ++k) {
        if (b_[k] >= 0) {
            int p = base[b_[k]] + r_[k];
            tsw[p] = p_[k];
        }
    }
}

// Pass B: one block per bucket. LDS counting-sort by local dst; the LDS histogram IS
// the in-degree -> emits dinv, rp, self-loops, and the bucket's contiguous edata region.
__global__ void sort_bucket(const int* __restrict__ tsw, const int* __restrict__ bstart,
                            float* __restrict__ dinv, int* __restrict__ rp,
                            int* __restrict__ edata, int N, int E, int nbk) {
    __shared__ int cnt[256];
    __shared__ int cursor[256];
    int b = blockIdx.x;
    int t = threadIdx.x;
    int estart = bstart[b];
    int eend = (b + 1 < nbk) ? bstart[b + 1] : E;

    cnt[t] = 0;
    __syncthreads();
    for (int i = estart + t; i < eend; i += 256) {
        atomicAdd(&cnt[(uint)tsw[i] >> 17], 1);
    }
    __syncthreads();

    int node = (b << BSHIFT) + t;
    int self = (node < N) ? 1 : 0;
    int deg = cnt[t];
    int v = deg + self;
    cursor[t] = v;
    __syncthreads();
    for (int o = 1; o < 256; o <<= 1) {
        int tv = (t >= o) ? cursor[t - o] : 0;
        __syncthreads();
        cursor[t] += tv;
        __syncthreads();
    }
    int ex = cursor[t] - v;                       // exclusive local offset
    int gbase = estart + (b << BSHIFT);           // edges + self loops before this bucket

    if (node < N) {
        dinv[node] = rsqrtf((float)(deg + 1));    // + self loop
        rp[node] = gbase + ex;
        edata[gbase + ex] = node;                 // self loop at slot 0 (src == dst)
    }
    if (b == nbk - 1 && t == 0) rp[N] = E + N;
    cursor[t] = ex + self;
    __syncthreads();

    for (int i = estart + t; i < eend; i += 256) {
        uint rec = (uint)tsw[i];
        int pos = gbase + atomicAdd(&cursor[rec >> 17], 1);
        edata[pos] = (int)(rec & 0x1FFFFu);
    }
}

// ---------------- MFMA GEMM layer 1: H1[row][0..128) = dinv[row] * (X[row] @ W1) ----------------
// Zeroes the pad row at index n (blockIdx 0).
// mfma_f32_16x16x32_bf16: A row=lane&15, k=(lane>>4)*8+i ; B col=lane&15, same k ;
// D col=lane&15, row=(lane>>4)*4+reg

__launch_bounds__(256)
__global__ void gemm_mfma128(const float* __restrict__ X, const ushort* __restrict__ Wimg,
                             ushort* __restrict__ H, const float* __restrict__ dinv, int n) {
    constexpr int NT = 8;
    if (blockIdx.x == 0 && threadIdx.x < 128) H[(size_t)n * 128 + threadIdx.x] = 0;
    __shared__ ushort sW[128 * 128];
    {
        const uint4* src = (const uint4*)Wimg;
        uint4* dst = (uint4*)sW;
        for (int i = threadIdx.x; i < 128 * 128 * 2 / 16; i += 256) dst[i] = src[i];
    }
    __syncthreads();

    const int w  = threadIdx.x >> 6;
    const int l  = threadIdx.x & 63;
    const int lm = l & 15, lk = l >> 4;
    const int row_base = blockIdx.x * 128 + w * 32;

    f32x4 acc[2][NT];
#pragma unroll
    for (int mt = 0; mt < 2; ++mt)
#pragma unroll
        for (int nt = 0; nt < NT; ++nt) {
            f32x4 z = {0.f, 0.f, 0.f, 0.f};
            acc[mt][nt] = z;
        }

    int r0 = row_base + lm;
    int r1 = row_base + 16 + lm;
    int r0c = r0 < n ? r0 : n - 1;
    int r1c = r1 < n ? r1 : n - 1;

#pragma unroll
    for (int kb = 0; kb < 4; ++kb) {
        short8v a0, a1;
        const float* p0 = X + (size_t)r0c * 128 + kb * 32 + lk * 8;
        const float* p1 = X + (size_t)r1c * 128 + kb * 32 + lk * 8;
        float4 u0 = *(const float4*)p0;
        float4 v0 = *(const float4*)(p0 + 4);
        float4 u1 = *(const float4*)p1;
        float4 v1 = *(const float4*)(p1 + 4);
        a0[0] = (short)f2bf(u0.x); a0[1] = (short)f2bf(u0.y);
        a0[2] = (short)f2bf(u0.z); a0[3] = (short)f2bf(u0.w);
        a0[4] = (short)f2bf(v0.x); a0[5] = (short)f2bf(v0.y);
        a0[6] = (short)f2bf(v0.z); a0[7] = (short)f2bf(v0.w);
        a1[0] = (short)f2bf(u1.x); a1[1] = (short)f2bf(u1.y);
        a1[2] = (short)f2bf(u1.z); a1[3] = (short)f2bf(u1.w);
        a1[4] = (short)f2bf(v1.x); a1[5] = (short)f2bf(v1.y);
        a1[6] = (short)f2bf(v1.z); a1[7] = (short)f2bf(v1.w);
#pragma unroll
        for (int nt = 0; nt < NT; ++nt) {
            int nn = nt * 16 + lm;
            uint byte = (uint)nn * 256u + (uint)kb * 64u + (uint)lk * 16u;
            byte ^= (uint)((nn & 7) << 4);
            short8v b = *(const short8v*)((const char*)sW + byte);
            acc[0][nt] = __builtin_amdgcn_mfma_f32_16x16x32_bf16(a0, b, acc[0][nt], 0, 0, 0);
            acc[1][nt] = __builtin_amdgcn_mfma_f32_16x16x32_bf16(a1, b, acc[1][nt], 0, 0, 0);
        }
    }

    float dvs[2][4];
#pragma unroll
    for (int mt = 0; mt < 2; ++mt)
#pragma unroll
        for (int r = 0; r < 4; ++r) {
            int row = row_base + mt * 16 + lk * 4 + r;
            dvs[mt][r] = (row < n) ? dinv[row] : 0.f;
        }
#pragma unroll
    for (int mt = 0; mt < 2; ++mt)
#pragma unroll
        for (int nt = 0; nt < NT; ++nt)
#pragma unroll
            for (int r = 0; r < 4; ++r) {
                int row = row_base + mt * 16 + lk * 4 + r;
                if (row < n) H[(size_t)row * 128 + nt * 16 + lm] = f2bf(acc[mt][nt][r] * dvs[mt][r]);
            }
}

// ---------------- fused layer-1 agg + layer-2 GEMM ----------------
// Gather phase: 16-lane quarter per node, uint4/lane, 16 loads in flight;
// computes A1row = relu(dinv[node]*sum H1[src] + b1) in registers.
// Pack to bf16 -> swizzled LDS tile sA[16][128]; barrier; each wave MFMAs the 16-node
// tile against W2 (LDS image) for its 16-col n-tile; writes H2 = dinv*(A1@W2).

__launch_bounds__(256)
__global__ void agg128_w2(const ushort* __restrict__ H, const int* __restrict__ rp,
                          const int* __restrict__ edata, const float* __restrict__ dinv,
                          const float* __restrict__ b1, const ushort* __restrict__ W2img,
                          ushort* __restrict__ H2, int N) {
    __shared__ ushort sW[64 * 128];   // 16KB W2 image (swizzled)
    __shared__ ushort sA[16 * 128];   // 4KB A1 tile (swizzled)
    {
        const uint4* s = (const uint4*)W2img;
        uint4* d = (uint4*)sW;
        for (int i = threadIdx.x; i < 64 * 128 * 2 / 16; i += 256) d[i] = s[i];
    }
    if (blockIdx.x == 0 && threadIdx.x < 64) H2[(size_t)N * 64 + threadIdx.x] = 0;

    const int lane = threadIdx.x & 63;
    const int c = lane & 15;                      // lane in quarter
    const int qb = lane & 48;                     // quarter base within wave
    const int nl = threadIdx.x >> 4;              // local node 0..15
    const int node = blockIdx.x * 16 + nl;

    float a0 = 0.f, a1 = 0.f, a2 = 0.f, a3 = 0.f;
    float a4 = 0.f, a5 = 0.f, a6 = 0.f, a7 = 0.f;

    if (node < N) {
        int e = rp[node], end = rp[node + 1];
        for (; e < end; e += 16) {
            int idx = e + c;
            int md = (idx < end) ? edata[idx] : N;    // zero row for padding slots
#pragma unroll
            for (int j = 0; j < 16; ++j) {
                int si = __shfl(md, qb + j);
                uint4 hv = *(const uint4*)&H[(size_t)si * 128 + c * 8];
                a0 += __uint_as_float(hv.x << 16);
                a1 += __uint_as_float(hv.x & 0xffff0000u);
                a2 += __uint_as_float(hv.y << 16);
                a3 += __uint_as_float(hv.y & 0xffff0000u);
                a4 += __uint_as_float(hv.z << 16);
                a5 += __uint_as_float(hv.z & 0xffff0000u);
                a6 += __uint_as_float(hv.w << 16);
                a7 += __uint_as_float(hv.w & 0xffff0000u);
            }
        }
        float dg = dinv[node];
        float4 bv0 = *(const float4*)&b1[c * 8];
        float4 bv1 = *(const float4*)&b1[c * 8 + 4];
        a0 = fmaxf(dg * a0 + bv0.x, 0.f); a1 = fmaxf(dg * a1 + bv0.y, 0.f);
        a2 = fmaxf(dg * a2 + bv0.z, 0.f); a3 = fmaxf(dg * a3 + bv0.w, 0.f);
        a4 = fmaxf(dg * a4 + bv1.x, 0.f); a5 = fmaxf(dg * a5 + bv1.y, 0.f);
        a6 = fmaxf(dg * a6 + bv1.z, 0.f); a7 = fmaxf(dg * a7 + bv1.w, 0.f);
    } else {
        a0 = a1 = a2 = a3 = a4 = a5 = a6 = a7 = 0.f;   // zero A rows for pad nodes
    }
    uint4 pk;
    pk.x = (uint)f2bf(a0) | ((uint)f2bf(a1) << 16);
    pk.y = (uint)f2bf(a2) | ((uint)f2bf(a3) << 16);
    pk.z = (uint)f2bf(a4) | ((uint)f2bf(a5) << 16);
    pk.w = (uint)f2bf(a6) | ((uint)f2bf(a7) << 16);
    uint wbyte = (uint)nl * 256u + (((uint)c * 16u) ^ ((uint)(nl & 7) << 4));
    *(uint4*)((char*)sA + wbyte) = pk;
    __syncthreads();

    // MFMA: 16 nodes x 128k @ 128k x 64 -> wave w computes cols [w*16, w*16+16)
    const int w  = threadIdx.x >> 6;
    const int lm = lane & 15, lk = lane >> 4;
    const int nn = w * 16 + lm;
    f32x4 acc = {0.f, 0.f, 0.f, 0.f};
#pragma unroll
    for (int kb = 0; kb < 4; ++kb) {
        uint ka = (uint)(kb * 64 + lk * 16);
        short8v af = *(const short8v*)((const char*)sA + (uint)lm * 256u + (ka ^ ((uint)(lm & 7) << 4)));
        short8v bf = *(const short8v*)((const char*)sW + (uint)nn * 256u + (ka ^ ((uint)(nn & 7) << 4)));
        acc = __builtin_amdgcn_mfma_f32_16x16x32_bf16(af, bf, acc, 0, 0, 0);
    }
#pragma unroll
    for (int r = 0; r < 4; ++r) {
        int n2 = blockIdx.x * 16 + lk * 4 + r;
        if (n2 < N) H2[(size_t)n2 * 64 + w * 16 + lm] = f2bf(acc[r] * dinv[n2]);
    }
}

// ---------------- layer-2 aggregation (round-12 agg64 form) ----------------
// H2 is [N+1][64] bf16 (pre-scaled by dinv[src]) with zero pad row at N.
// out[node] = dinv[node] * sum_e H2[src_e] + b2; fp32 out.
// One node per 16-lane QUARTER (16 lanes x uint2 = full 128B row); 16 loads in flight.

__launch_bounds__(256)
__global__ void agg64(const ushort* __restrict__ H, const int* __restrict__ rp,
                      const int* __restrict__ edata, const float* __restrict__ dinv,
                      const float* __restrict__ bias, float* __restrict__ out, int N) {
    const int lane = threadIdx.x & 63;
    const int qb = lane & 48;
    const int c = lane & 15;
    const int node = blockIdx.x * 16 + (threadIdx.x >> 4);
    if (node >= N) return;
    int e = rp[node], end = rp[node + 1];
    float a0 = 0.f, a1 = 0.f, a2 = 0.f, a3 = 0.f;

    for (; e < end; e += 16) {
        int idx = e + c;
        int md = (idx < end) ? edata[idx] : N;
#pragma unroll
        for (int j = 0; j < 16; ++j) {
            int si = __shfl(md, qb + j);
            uint2 hv = *(const uint2*)&H[(size_t)si * 64 + c * 4];
            a0 += __uint_as_float(hv.x << 16);
            a1 += __uint_as_float(hv.x & 0xffff0000u);
            a2 += __uint_as_float(hv.y << 16);
            a3 += __uint_as_float(hv.y & 0xffff0000u);
        }
    }
    float dg = dinv[node];
    float4 bv = *(const float4*)&bias[c * 4];
    a0 = dg * a0 + bv.x; a1 = dg * a1 + bv.y;
    a2 = dg * a2 + bv.z; a3 = dg * a3 + bv.w;
    *(float4*)&out[(size_t)node * 64 + c * 4] = make_float4(a0, a1, a2, a3);
}

__global__ void zero_out(float* __restrict__ out, int n) {
    int i = blockIdx.x * 256 + threadIdx.x;
    if (i < n) out[i] = 0.f;
}

// ---------------- launch ----------------

extern "C" void kernel_launch(void* const* d_in, const int* in_sizes, int n_in,
                              void* d_out, int out_size, void* d_ws, size_t ws_size,
                              hipStream_t stream) {
    const float* x  = (const float*)d_in[0];
    const int*   ei = (const int*)d_in[1];
    const float* W1 = (const float*)d_in[2];
    const float* b1 = (const float*)d_in[3];
    const float* W2 = (const float*)d_in[4];
    const float* b2 = (const float*)d_in[5];
    float* out = (float*)d_out;

    const int N = in_sizes[0] / 128;
    const int E = in_sizes[1] / 2;
    const int* srcp = ei;
    const int* dstp = ei + E;

    char* base = (char*)d_ws;
    size_t off = 0;
    auto alloc = [&](size_t bytes) -> void* {
        void* p = base + off;
        off += (bytes + 15) & ~(size_t)15;
        return p;
    };
    ushort* H1    = (ushort*)alloc((size_t)(N + 1) * 128 * 2);  // [N+1][128] + pad row
    ushort* H2    = (ushort*)alloc((size_t)(N + 1) * 64 * 2);   // [N+1][64] + pad row; aliases tsw
    ushort* Wt1s  = (ushort*)alloc(128 * 128 * 2);
    ushort* Wt2s  = (ushort*)alloc(64 * 128 * 2);
    float*  dinv  = (float*)alloc((size_t)N * 4);
    int*    rp    = (int*)alloc((size_t)(N + 1) * 4);
    int*    bcnt  = (int*)alloc(NBMAX * 4);
    int*    bstart= (int*)alloc(NBMAX * 4);
    int*    bcur  = (int*)alloc(NBMAX * 4);
    int*    edata = (int*)alloc((size_t)(E + N) * 4);

    int* tsw = (int*)H2;   // E records of 4B, dead before agg128_w2 writes H2

    int nbk = (N + (1 << BSHIFT) - 1) >> BSHIFT;
    if (off > ws_size || (size_t)E * 4 > (size_t)(N + 1) * 128 ||
        N > (1 << 17) || nbk > NBMAX) {
        zero_out<<<(out_size + 255) / 256, 256, 0, stream>>>(out, out_size);
        return;
    }
    int nchunk = (E + 4095) / 4096;

    hipMemsetAsync(bcnt, 0, NBMAX * sizeof(int), stream);
    hist_prep<<<nchunk, 256, 0, stream>>>(dstp, bcnt, E, nbk, W1, W2, Wt1s, Wt2s);
    bucket_scan<<<1, 512, 0, stream>>>(bcnt, bstart, bcur, nbk);
    bucket_scatter<<<nchunk, 256, 0, stream>>>(srcp, dstp, bcur, tsw, E);
    sort_bucket<<<nbk, 256, 0, stream>>>(tsw, bstart, dinv, rp, edata, N, E, nbk);

    gemm_mfma128<<<(N + 127) / 128, 256, 0, stream>>>(x, Wt1s, H1, dinv, N);
    agg128_w2<<<(N + 15) / 16, 256, 0, stream>>>(H1, rp, edata, dinv, b1, Wt2s, H2, N);
    agg64<<<(N + 15) / 16, 256, 0, stream>>>(H2, rp, edata, dinv, b2, out, N);
}